// Round 1
// 2155.844 us; speedup vs baseline: 1.5920x; 1.5920x over previous
//
#include <hip/hip_runtime.h>
#include <math.h>

#define TFULL 2049
#define TCTX  2048
#define Vm    50257

typedef __attribute__((ext_vector_type(8))) short bf16x8;
typedef __attribute__((ext_vector_type(4))) float f32x4;

__device__ __forceinline__ float wred64(float v){
  #pragma unroll
  for (int m = 1; m < 64; m <<= 1) v += __shfl_xor(v, m, 64);
  return v;
}
__device__ __forceinline__ short bf16_rn(float x){
  union { float f; unsigned u; } c; c.f = x;
  unsigned r = c.u + 0x7fff + ((c.u >> 16) & 1);
  return (short)(r >> 16);
}
__device__ __forceinline__ float bf16_f(short s){
  union { float f; unsigned u; } c; c.u = ((unsigned)(unsigned short)s) << 16;
  return c.f;
}

#define FMA4(ACC_, S_, W_)                         \
  (ACC_).x = fmaf((S_), (W_).x, (ACC_).x);         \
  (ACC_).y = fmaf((S_), (W_).y, (ACC_).y);         \
  (ACC_).z = fmaf((S_), (W_).z, (ACC_).z);         \
  (ACC_).w = fmaf((S_), (W_).w, (ACC_).w);

// --------------------------------------------- K0: folded scalars + gammaWg
__global__ void k0_setup(const float* __restrict__ gamma, const float* __restrict__ beta,
                         const float* __restrict__ Wg, float* __restrict__ scal){
  const int t = threadIdx.x;        // 512 threads
  float wg = Wg[t];
  float g  = gamma[t]*wg, bw = beta[t]*wg;
  scal[2 + t] = g;                  // gamma*Wg table
  g = wred64(g); bw = wred64(bw);
  __shared__ float ra[8], rb[8];
  if ((t & 63) == 0){ ra[t>>6] = g; rb[t>>6] = bw; }
  __syncthreads();
  if (t == 0){
    float G = 0.f, Bw = 0.f;
    #pragma unroll
    for (int i = 0; i < 8; ++i){ G += ra[i]; Bw += rb[i]; }
    scal[0] = G; scal[1] = Bw;
  }
}

// ---------------------- K0b: split W into bf16 hi/lo, packed B-fragment order
// Layout: [kb][n][kq][j] (j contiguous, 8 shorts = 16B per fragment slice).
// Element (k = kb*32 + kq*8 + j, n) of W[K][N].
__global__ __launch_bounds__(256) void kpack(const float* __restrict__ W, int N, int KB,
                                             short* __restrict__ hi, short* __restrict__ lo){
  int i = blockIdx.x*256 + threadIdx.x;   // over KB*N*4 (kb,n,kq)
  if (i >= KB*N*4) return;
  int kq = i & 3;
  int n  = (i >> 2) % N;
  int kb = i / (N*4);
  const float* src = W + (kb*32 + kq*8)*N + n;
  bf16x8 h8, l8;
  #pragma unroll
  for (int j = 0; j < 8; ++j){
    float w = src[j*N];
    short h = bf16_rn(w);
    h8[j] = h;
    l8[j] = bf16_rn(w - bf16_f(h));
  }
  *(bf16x8*)(hi + i*8) = h8;
  *(bf16x8*)(lo + i*8) = l8;
}

// ------------------------------------------------- K1: fused FF+LN+gate tile
// 32 tokens/block, 512 thr (8 waves), 1 block/CU. MFMA 16x16x32 bf16 hi/lo
// (3 products). Two 16-row M-tiles share every B fragment (MFMA:Bload = 3:1),
// and block count halves vs the 16-token version => weight L2/L3 stream 32->16GB.
// A LDS planes: [kb(16)][tok(32) stride 40][kq(4)][j(8)]  (80B tok stride)
// R LDS planes: [kb(8)][tok(32) stride 32][kq(4)][j(8)]
__global__ __launch_bounds__(512, 2) void k1_main(
    const int*   __restrict__ seq,   const float* __restrict__ temp,
    const float* __restrict__ gumbel,const float* __restrict__ embed,
    const short* __restrict__ W1h,   const short* __restrict__ W1l,
    const float* __restrict__ b1,
    const short* __restrict__ W2h,   const short* __restrict__ W2l,
    const float* __restrict__ b2,
    const float* __restrict__ gamma, const float* __restrict__ beta,
    const float* __restrict__ bg,
    const float* __restrict__ scal,
    float* __restrict__ pert, float* __restrict__ qh)
{
  __shared__ short Ah[16*1280];  // 40KB
  __shared__ short Al[16*1280];  // 40KB
  __shared__ short Rh[8*1024];   // 16KB
  __shared__ short Rl[8*1024];   // 16KB
  __shared__ float Xq[512];      // x of the qh token (if any)
  __shared__ int   srow[32];
  __shared__ float redS1[256], redS2[256], redSG[256];
  __shared__ float redMu[32], redRs[32];

  const int t    = threadIdx.x;
  const int tile = blockIdx.x;
  const int lane = t & 63;
  const int wv   = t >> 6;        // 0..7
  const int mrow = lane & 15;     // A-frag m / C col / B-frag n
  const int kq   = lane >> 4;     // k-quad
  const int crow0 = kq*4;         // C rows

  if (t < 32) srow[t] = seq[tile*32 + t];
  __syncthreads();

  // ---- stage 32 embed rows -> hi/lo A planes in fragment order ----
  const f32x4* __restrict__ embv = (const f32x4*)embed;
  #pragma unroll
  for (int k = 0; k < 8; ++k){
    int f4  = k*512 + t;                 // 4096 float4 = 32 tok x 128
    int tok = f4 >> 7, c4 = f4 & 127;
    f32x4 v = __builtin_nontemporal_load(embv + srow[tok]*128 + c4);
    int d0 = c4*4;
    int base = (d0>>5)*1280 + tok*40 + ((d0>>3)&3)*8 + (d0&7);
    short h0 = bf16_rn(v[0]), h1 = bf16_rn(v[1]), h2 = bf16_rn(v[2]), h3 = bf16_rn(v[3]);
    Ah[base+0] = h0; Ah[base+1] = h1; Ah[base+2] = h2; Ah[base+3] = h3;
    Al[base+0] = bf16_rn(v[0] - bf16_f(h0));
    Al[base+1] = bf16_rn(v[1] - bf16_f(h1));
    Al[base+2] = bf16_rn(v[2] - bf16_f(h2));
    Al[base+3] = bf16_rn(v[3] - bf16_f(h3));
  }
  __syncthreads();

  f32x4 ff[4][2];  // x partial: [nt][mt]; d = wv*64 + nt*16 + mrow, tok = mt*16 + kq*4 + r
  #pragma unroll
  for (int i = 0; i < 4; ++i){
    ff[i][0] = (f32x4){0.f,0.f,0.f,0.f};
    ff[i][1] = (f32x4){0.f,0.f,0.f,0.f};
  }

  for (int ch = 0; ch < 4; ++ch){
    // ---------- GEMM1: a[32 x 256chunk] ----------
    f32x4 acc[2][2];   // [nt][mt]
    #pragma unroll
    for (int i = 0; i < 2; ++i){
      acc[i][0] = (f32x4){0.f,0.f,0.f,0.f};
      acc[i][1] = (f32x4){0.f,0.f,0.f,0.f};
    }
    #pragma unroll 2
    for (int kb = 0; kb < 16; ++kb){
      bf16x8 ah0 = *(const bf16x8*)(Ah + kb*1280 + mrow*40 + kq*8);
      bf16x8 al0 = *(const bf16x8*)(Al + kb*1280 + mrow*40 + kq*8);
      bf16x8 ah1 = *(const bf16x8*)(Ah + kb*1280 + (mrow+16)*40 + kq*8);
      bf16x8 al1 = *(const bf16x8*)(Al + kb*1280 + (mrow+16)*40 + kq*8);
      #pragma unroll
      for (int nt = 0; nt < 2; ++nt){
        int n = ch*256 + wv*32 + nt*16 + mrow;
        int off = (((kb<<10) + n)*4 + kq)*8;
        bf16x8 bh = *(const bf16x8*)(W1h + off);
        bf16x8 bl = *(const bf16x8*)(W1l + off);
        acc[nt][0] = __builtin_amdgcn_mfma_f32_16x16x32_bf16(ah0, bh, acc[nt][0], 0,0,0);
        acc[nt][0] = __builtin_amdgcn_mfma_f32_16x16x32_bf16(al0, bh, acc[nt][0], 0,0,0);
        acc[nt][0] = __builtin_amdgcn_mfma_f32_16x16x32_bf16(ah0, bl, acc[nt][0], 0,0,0);
        acc[nt][1] = __builtin_amdgcn_mfma_f32_16x16x32_bf16(ah1, bh, acc[nt][1], 0,0,0);
        acc[nt][1] = __builtin_amdgcn_mfma_f32_16x16x32_bf16(al1, bh, acc[nt][1], 0,0,0);
        acc[nt][1] = __builtin_amdgcn_mfma_f32_16x16x32_bf16(ah1, bl, acc[nt][1], 0,0,0);
      }
    }
    __syncthreads();              // prior GEMM2 done reading R
    // relu + bias -> R planes (fragment order for GEMM2)
    #pragma unroll
    for (int nt = 0; nt < 2; ++nt){
      int jcol = wv*32 + nt*16 + mrow;        // 0..255 chunk-local
      float bb = b1[ch*256 + jcol];
      int rbase = (jcol>>5)*1024 + ((jcol>>3)&3)*8 + (jcol&7);
      #pragma unroll
      for (int mt = 0; mt < 2; ++mt){
        #pragma unroll
        for (int r = 0; r < 4; ++r){
          int tok = mt*16 + crow0 + r;
          float a = fmaxf(acc[nt][mt][r] + bb, 0.f);
          short h = bf16_rn(a);
          Rh[rbase + tok*32] = h;
          Rl[rbase + tok*32] = bf16_rn(a - bf16_f(h));
        }
      }
    }
    __syncthreads();
    // ---------- GEMM2 partial: ff += relu . W2[chunk rows] ----------
    #pragma unroll 2
    for (int kb = 0; kb < 8; ++kb){
      bf16x8 ah0 = *(const bf16x8*)(Rh + kb*1024 + mrow*32 + kq*8);
      bf16x8 al0 = *(const bf16x8*)(Rl + kb*1024 + mrow*32 + kq*8);
      bf16x8 ah1 = *(const bf16x8*)(Rh + kb*1024 + (mrow+16)*32 + kq*8);
      bf16x8 al1 = *(const bf16x8*)(Rl + kb*1024 + (mrow+16)*32 + kq*8);
      int kbg = ch*8 + kb;
      #pragma unroll
      for (int nt = 0; nt < 4; ++nt){
        int n = wv*64 + nt*16 + mrow;
        int off = (((kbg<<9) + n)*4 + kq)*8;
        bf16x8 bh = *(const bf16x8*)(W2h + off);
        bf16x8 bl = *(const bf16x8*)(W2l + off);
        ff[nt][0] = __builtin_amdgcn_mfma_f32_16x16x32_bf16(ah0, bh, ff[nt][0], 0,0,0);
        ff[nt][0] = __builtin_amdgcn_mfma_f32_16x16x32_bf16(al0, bh, ff[nt][0], 0,0,0);
        ff[nt][0] = __builtin_amdgcn_mfma_f32_16x16x32_bf16(ah0, bl, ff[nt][0], 0,0,0);
        ff[nt][1] = __builtin_amdgcn_mfma_f32_16x16x32_bf16(ah1, bh, ff[nt][1], 0,0,0);
        ff[nt][1] = __builtin_amdgcn_mfma_f32_16x16x32_bf16(al1, bh, ff[nt][1], 0,0,0);
        ff[nt][1] = __builtin_amdgcn_mfma_f32_16x16x32_bf16(ah1, bl, ff[nt][1], 0,0,0);
      }
    }
  }

  // ---------------- epilogue ----------------
  const float G1 = scal[0], BW = scal[1];
  const float* gWg = scal + 2;
  const float bgv  = bg[0];
  const float invT = 1.0f / temp[0];
  // qh token in this block (at most one): pos == 2048
  int rem  = (tile*32) % 2049;
  int qtok = 2048 - rem;          // valid if < 32

  float ps1[2][4], ps2[2][4], psg[2][4];
  #pragma unroll
  for (int mt = 0; mt < 2; ++mt)
    #pragma unroll
    for (int r = 0; r < 4; ++r){ ps1[mt][r]=0.f; ps2[mt][r]=0.f; psg[mt][r]=0.f; }

  #pragma unroll
  for (int nt = 0; nt < 4; ++nt){
    int d = wv*64 + nt*16 + mrow;
    float b2v = b2[d];
    float gw  = gWg[d];
    int abase = (d>>5)*1280 + ((d>>3)&3)*8 + (d&7);
    #pragma unroll
    for (int mt = 0; mt < 2; ++mt){
      #pragma unroll
      for (int r = 0; r < 4; ++r){
        int tok = mt*16 + crow0 + r;
        float h = bf16_f(Ah[abase + tok*40]) + bf16_f(Al[abase + tok*40]);
        float x = h + ff[nt][mt][r] + b2v;
        ps1[mt][r] += x;
        ps2[mt][r] = fmaf(x, x, ps2[mt][r]);
        psg[mt][r] = fmaf(x, gw, psg[mt][r]);
        if (tok == qtok) Xq[d] = x;
      }
    }
  }
  // reduce over mrow (lane bits 0..3)
  #pragma unroll
  for (int mt = 0; mt < 2; ++mt){
    #pragma unroll
    for (int r = 0; r < 4; ++r){
      float a = ps1[mt][r], b = ps2[mt][r], c = psg[mt][r];
      #pragma unroll
      for (int m = 1; m < 16; m <<= 1){
        a += __shfl_xor(a, m, 64);
        b += __shfl_xor(b, m, 64);
        c += __shfl_xor(c, m, 64);
      }
      if (mrow == 0){
        int tok = mt*16 + crow0 + r;
        redS1[tok*8 + wv] = a;
        redS2[tok*8 + wv] = b;
        redSG[tok*8 + wv] = c;
      }
    }
  }
  __syncthreads();

  if (t < 32){
    float S1 = 0.f, S2 = 0.f, SG = 0.f;
    #pragma unroll
    for (int w = 0; w < 8; ++w){
      S1 += redS1[t*8 + w];
      S2 += redS2[t*8 + w];
      SG += redSG[t*8 + w];
    }
    float mu  = S1 * (1.f/512.f);
    float var = S2 * (1.f/512.f) - mu*mu;
    float rs  = rsqrtf(var + 1e-5f);
    redMu[t] = mu; redRs[t] = rs;
    int id  = tile*32 + t;
    int b   = id / 2049;
    int pos = id - b*2049;
    if (pos < TCTX){
      float gate = rs*(SG - mu*G1) + BW + bgv;
      float pv = (gate + __builtin_nontemporal_load(gumbel + b*TCTX + pos)) * invT;
      __builtin_nontemporal_store(pv, pert + b*TCTX + pos);
    }
  }
  __syncthreads();

  if (qtok < 32 && t < 256){
    int id = tile*32 + qtok;
    int b  = id / 2049;
    float mu = redMu[qtok], rs = redRs[qtok];
    int d = t*2;
    qh[b*512 + d]     = (Xq[d]  -mu)*rs*gamma[d]   + beta[d];
    qh[b*512 + d + 1] = (Xq[d+1]-mu)*rs*gamma[d+1] + beta[d+1];
  }
}

// ---------------------------------------------------------------- K2: top-3
__global__ __launch_bounds__(256) void k2_topk(const float* __restrict__ pert,
                                               int* __restrict__ idxw){
  __shared__ float v[2048];
  __shared__ float wvv[256];
  __shared__ int   wii[256];
  const int b = blockIdx.x, t = threadIdx.x;
  for (int i = t; i < 2048; i += 256) v[i] = pert[b*TCTX + i];
  __syncthreads();
  for (int r = 0; r < 3; ++r){
    float best = -INFINITY; int bi = 1<<30;
    for (int i = t; i < 2048; i += 256){
      float x = v[i];
      if (x > best || (x == best && i < bi)){ best = x; bi = i; }
    }
    wvv[t] = best; wii[t] = bi;
    __syncthreads();
    for (int s = 128; s > 0; s >>= 1){
      if (t < s){
        float ov = wvv[t+s]; int oi = wii[t+s];
        if (ov > wvv[t] || (ov == wvv[t] && oi < wii[t])){ wvv[t] = ov; wii[t] = oi; }
      }
      __syncthreads();
    }
    if (t == 0){ idxw[b*3 + r] = wii[0]; v[wii[0]] = -INFINITY; }
    __syncthreads();
  }
}

// -------------------------------------- K3: recompute hiddens for top-3 rows
__global__ __launch_bounds__(256) void k3_rows(const int* __restrict__ seq,
    const float* __restrict__ embed, const float* __restrict__ W1, const float* __restrict__ b1,
    const float* __restrict__ W2,    const float* __restrict__ b2,
    const float* __restrict__ gamma, const float* __restrict__ beta,
    const int* __restrict__ idxw, float* __restrict__ memr)
{
  __shared__ float hs[512];
  __shared__ float rbuf[1024];
  __shared__ float red1[4], red2[4];
  const int t   = threadIdx.x;
  const int blk = blockIdx.x;
  const int b = blk / 3, kk = blk - b*3;
  const int pos = idxw[b*3 + kk];
  const int row = seq[b*TFULL + pos];
  ((float2*)hs)[t] = ((const float2*)(embed + row*512))[t];
  __syncthreads();
  const float4* W1v = (const float4*)W1;
  float4 a = make_float4(0,0,0,0);
  #pragma unroll 4
  for (int d = 0; d < 512; ++d){
    float xb = hs[d];
    float4 wq = W1v[d*256 + t];
    FMA4(a, xb, wq);
  }
  float4 bq = ((const float4*)b1)[t];
  float4 r;
  r.x = fmaxf(a.x+bq.x, 0.f); r.y = fmaxf(a.y+bq.y, 0.f);
  r.z = fmaxf(a.z+bq.z, 0.f); r.w = fmaxf(a.w+bq.w, 0.f);
  ((float4*)rbuf)[t] = r;
  __syncthreads();
  const float2* W2v2 = (const float2*)W2;
  float fx = 0.f, fy = 0.f;
  #pragma unroll 4
  for (int j = 0; j < 1024; ++j){
    float rb = rbuf[j];
    float2 wq = W2v2[j*256 + t];
    fx = fmaf(rb, wq.x, fx); fy = fmaf(rb, wq.y, fy);
  }
  float2 b2q = ((const float2*)b2)[t];
  float2 hx  = ((float2*)hs)[t];
  float x0 = hx.x + fx + b2q.x;
  float x1 = hx.y + fy + b2q.y;
  float s1 = wred64(x0 + x1);
  float s2 = wred64(x0*x0 + x1*x1);
  if ((t & 63) == 0){ red1[t>>6] = s1; red2[t>>6] = s2; }
  __syncthreads();
  float S1 = red1[0]+red1[1]+red1[2]+red1[3];
  float S2 = red2[0]+red2[1]+red2[2]+red2[3];
  float mu  = S1*(1.f/512.f);
  float var = S2*(1.f/512.f) - mu*mu;
  float rs  = rsqrtf(var + 1e-5f);
  const int dd = t*2;
  memr[(b*3+kk)*512 + dd]     = (x0-mu)*rs*gamma[dd]   + beta[dd];
  memr[(b*3+kk)*512 + dd + 1] = (x1-mu)*rs*gamma[dd+1] + beta[dd+1];
}

// ------------------------------------------- K4: q, slot attention, ctx (T)
__global__ __launch_bounds__(256) void k4_attn(const float* __restrict__ qh,
    const float* __restrict__ Wr, const float* __restrict__ br,
    const float* __restrict__ memr, float* __restrict__ ctxT)
{
  __shared__ float hq[512];
  __shared__ float red[12];
  const int t = threadIdx.x, b = blockIdx.x;
  ((float2*)hq)[t] = ((const float2*)(qh + b*512))[t];
  __syncthreads();
  const float2* Wrv = (const float2*)Wr;
  float qx = 0.f, qy = 0.f;
  #pragma unroll 4
  for (int d = 0; d < 512; ++d){
    float hb = hq[d];
    float2 wq = Wrv[d*256 + t];
    qx = fmaf(hb, wq.x, qx); qy = fmaf(hb, wq.y, qy);
  }
  float2 brq = ((const float2*)br)[t];
  qx += brq.x; qy += brq.y;
  const int dd = t*2;
  const float* m0 = memr + (b*3+0)*512;
  const float* m1 = memr + (b*3+1)*512;
  const float* m2 = memr + (b*3+2)*512;
  float p0 = wred64(qx*m0[dd] + qy*m0[dd+1]);
  float p1 = wred64(qx*m1[dd] + qy*m1[dd+1]);
  float p2 = wred64(qx*m2[dd] + qy*m2[dd+1]);
  if ((t & 63) == 0){ int w = t>>6; red[w*3+0]=p0; red[w*3+1]=p1; red[w*3+2]=p2; }
  __syncthreads();
  float s0 = red[0]+red[3]+red[6]+red[9];
  float s1 = red[1]+red[4]+red[7]+red[10];
  float s2 = red[2]+red[5]+red[8]+red[11];
  float m  = fmaxf(fmaxf(s0, s1), fmaxf(s2, 0.f));
  float e0 = expf(s0-m), e1 = expf(s1-m), e2 = expf(s2-m);
  float den = e0 + e1 + e2 + 13.f*expf(-m);   // 13 empty slots
  float a0 = e0/den, a1 = e1/den, a2 = e2/den;
  float c0 = a0*m0[dd]   + a1*m1[dd]   + a2*m2[dd];
  float c1 = a0*m0[dd+1] + a1*m1[dd+1] + a2*m2[dd+1];
  ctxT[dd*64 + b]     = c0;
  ctxT[(dd+1)*64 + b] = c1;
}

// ----------------------------------------------------- K5: out = ctx@Wo + bo
__global__ __launch_bounds__(256) void k5_out(const float* __restrict__ ctxT,
    const float* __restrict__ Wo, const float* __restrict__ bo,
    float* __restrict__ out)
{
  const int v  = blockIdx.x*256 + threadIdx.x;
  const int vc = v < Vm ? v : Vm-1;
  float acc[64];
  #pragma unroll
  for (int b = 0; b < 64; ++b) acc[b] = 0.f;
  for (int d = 0; d < 512; ++d){
    float w = Wo[d*Vm + vc];
    const float* c = ctxT + d*64;
    #pragma unroll
    for (int b = 0; b < 64; ++b) acc[b] = fmaf(c[b], w, acc[b]);
  }
  if (v < Vm){
    float bb = bo[v];
    #pragma unroll
    for (int b = 0; b < 64; ++b) out[b*Vm + v] = acc[b] + bb;
  }
}

extern "C" void kernel_launch(void* const* d_in, const int* in_sizes, int n_in,
                              void* d_out, int out_size, void* d_ws, size_t ws_size,
                              hipStream_t stream){
  (void)in_sizes; (void)n_in; (void)out_size; (void)ws_size;
  const int*   seq   = (const int*)d_in[0];
  const float* temp  = (const float*)d_in[1];
  const float* gum   = (const float*)d_in[2];
  const float* embed = (const float*)d_in[3];
  const float* W1    = (const float*)d_in[4];
  const float* b1    = (const float*)d_in[5];
  const float* W2    = (const float*)d_in[6];
  const float* b2    = (const float*)d_in[7];
  const float* gamma = (const float*)d_in[8];
  const float* beta  = (const float*)d_in[9];
  const float* Wg    = (const float*)d_in[10];
  const float* bg    = (const float*)d_in[11];
  const float* Wr    = (const float*)d_in[12];
  const float* br    = (const float*)d_in[13];
  const float* Wo    = (const float*)d_in[14];
  const float* bo    = (const float*)d_in[15];
  float* out = (float*)d_out;

  float* wsf  = (float*)d_ws;
  float* pert = wsf;                    // 131072
  float* qh   = wsf + 131072;           // 32768
  float* memr = wsf + 163840;           // 98304
  float* ctxT = wsf + 262144;           // 32768
  float* scal = wsf + 294912;           // 1024 (uses 514)
  int*   idxw = (int*)(wsf + 295936);   // 256 ints
  short* W1h  = (short*)(wsf + 296192); // 512*1024 shorts each plane
  short* W1l  = W1h + 512*1024;
  short* W2h  = W1l + 512*1024;
  short* W2l  = W2h + 1024*512;

  k0_setup<<<1, 512, 0, stream>>>(gamma, beta, Wg, scal);
  kpack<<<256, 256, 0, stream>>>(W1, 1024, 16, W1h, W1l);
  kpack<<<256, 256, 0, stream>>>(W2, 512, 32, W2h, W2l);
  k1_main<<<4098, 512, 0, stream>>>(seq, temp, gum, embed, W1h, W1l, b1,
                                    W2h, W2l, b2, gamma, beta, bg, scal, pert, qh);
  k2_topk<<<64, 256, 0, stream>>>(pert, idxw);
  k3_rows<<<192, 256, 0, stream>>>(seq, embed, W1, b1, W2, b2, gamma, beta, idxw, memr);
  k4_attn<<<64, 256, 0, stream>>>(qh, Wr, br, memr, ctxT);
  k5_out<<<197, 256, 0, stream>>>(ctxT, Wo, bo, out);
}